// Round 1
// baseline (660.079 us; speedup 1.0000x reference)
//
#include <hip/hip_runtime.h>
#include <cstdint>
#include <cstddef>

#define F_IN 512
#define F_HID 32
#define N_CLS 16

// ---------------- edge dtype detection (int32 vs int64) ----------------
// int64 little-endian values < 2^31 have zero high words at odd int32 slots.
__global__ void k_detect(const int* e, int* flag) {
    if (threadIdx.x == 0 && blockIdx.x == 0) {
        int zeros = 0;
        for (int i = 0; i < 1024; ++i) if (e[2 * i + 1] == 0) zeros++;
        *flag = (zeros >= 1016) ? 1 : 0;
    }
}

__device__ __forceinline__ int edge_get(const void* e, int is64, long long idx) {
    return is64 ? (int)((const long long*)e)[idx] : ((const int*)e)[idx];
}

// ---------------- degree histogram ----------------
__global__ void k_hist(const void* edges, const int* flag, int* counts, int E) {
    int is64 = *flag;
    long long i = (long long)blockIdx.x * blockDim.x + threadIdx.x;
    long long step = (long long)gridDim.x * blockDim.x;
    for (; i < E; i += step) {
        int d = edge_get(edges, is64, (long long)E + i);
        atomicAdd(&counts[d], 1);
    }
}

// ---------------- dinv = rsqrt(deg+1) ----------------
__global__ void k_dinv(const int* counts, float* dinv, int n) {
    int i = blockIdx.x * blockDim.x + threadIdx.x;
    if (i < n) dinv[i] = rsqrtf((float)counts[i] + 1.0f);
}

// ---------------- 3-kernel exclusive scan (chunk = 1024/block) ----------------
__global__ void k_scan1(const int* counts, int* bsums, int n) {
    int base = blockIdx.x * 1024;
    int t = threadIdx.x;
    int s = 0;
#pragma unroll
    for (int j = 0; j < 4; ++j) {
        int i = base + t * 4 + j;
        if (i < n) s += counts[i];
    }
#pragma unroll
    for (int off = 32; off; off >>= 1) s += __shfl_down(s, off, 64);
    __shared__ int ws[4];
    if ((t & 63) == 0) ws[t >> 6] = s;
    __syncthreads();
    if (t == 0) bsums[blockIdx.x] = ws[0] + ws[1] + ws[2] + ws[3];
}

__global__ void k_scan2(int* bsums, int nb) {  // single block, 128 threads, nb<=128
    __shared__ int tmp[128];
    int t = threadIdx.x;
    int v = (t < nb) ? bsums[t] : 0;
    tmp[t] = v;
    __syncthreads();
    for (int off = 1; off < 128; off <<= 1) {
        int add = (t >= off) ? tmp[t - off] : 0;
        __syncthreads();
        tmp[t] += add;
        __syncthreads();
    }
    if (t < nb) bsums[t] = tmp[t] - v;  // exclusive
}

__global__ void k_scan3(const int* counts, const int* bsums, int* row_ptr, int n, int E) {
    int base = blockIdx.x * 1024;
    int t = threadIdx.x, lane = t & 63, wid = t >> 6;
    int c[4];
    int tsum = 0;
#pragma unroll
    for (int j = 0; j < 4; ++j) {
        int i = base + t * 4 + j;
        c[j] = (i < n) ? counts[i] : 0;
        tsum += c[j];
    }
    int incl = tsum;
#pragma unroll
    for (int off = 1; off < 64; off <<= 1) {
        int u = __shfl_up(incl, off, 64);
        if (lane >= off) incl += u;
    }
    __shared__ int ws[4];
    if (lane == 63) ws[wid] = incl;
    __syncthreads();
    int woff = 0;
#pragma unroll
    for (int wv = 0; wv < 4; ++wv)
        if (wv < wid) woff += ws[wv];
    int excl = incl - tsum + woff + bsums[blockIdx.x];
#pragma unroll
    for (int j = 0; j < 4; ++j) {
        int i = base + t * 4 + j;
        if (i < n) row_ptr[i] = excl;
        excl += c[j];
    }
    if (blockIdx.x == 0 && t == 0) row_ptr[n] = E;
}

// ---------------- CSR fill ----------------
__global__ void k_fill(const void* edges, const int* flag, const int* row_ptr,
                       int* cursor, int* csr, int E) {
    int is64 = *flag;
    long long i = (long long)blockIdx.x * blockDim.x + threadIdx.x;
    long long step = (long long)gridDim.x * blockDim.x;
    for (; i < E; i += step) {
        int s = edge_get(edges, is64, i);
        int d = edge_get(edges, is64, (long long)E + i);
        int p = row_ptr[d] + atomicAdd(&cursor[d], 1);
        csr[p] = s;
    }
}

// ---------------- GEMM1: hs1 = (x @ W1) * dinv[row]  [N,512]x[512,32] ----------------
__global__ __launch_bounds__(64) void k_gemm1(const float* __restrict__ x,
                                              const float* __restrict__ W,
                                              const float* __restrict__ dinv,
                                              float* __restrict__ hs1, int N) {
    int row = blockIdx.x * 64 + threadIdx.x;
    if (row >= N) return;
    const float4* xr = (const float4*)(x + (size_t)row * F_IN);
    float acc[32];
#pragma unroll
    for (int c = 0; c < 32; ++c) acc[c] = 0.f;

    float4 v0 = xr[0], v1 = xr[1], v2 = xr[2], v3 = xr[3];
    for (int k4 = 0; k4 < 128; k4 += 4) {
        float4 n0, n1, n2, n3;
        if (k4 + 4 < 128) {
            n0 = xr[k4 + 4]; n1 = xr[k4 + 5]; n2 = xr[k4 + 6]; n3 = xr[k4 + 7];
        } else {
            n0 = v0; n1 = v1; n2 = v2; n3 = v3;
        }
        const float* wr = W + k4 * 32 * 4;  // 4 k-rows of 32
#pragma unroll
        for (int c = 0; c < 32; ++c) {
            acc[c] = fmaf(v0.x, wr[0 * 32 + c], acc[c]);
            acc[c] = fmaf(v0.y, wr[1 * 32 + c], acc[c]);
            acc[c] = fmaf(v0.z, wr[2 * 32 + c], acc[c]);
            acc[c] = fmaf(v0.w, wr[3 * 32 + c], acc[c]);
            acc[c] = fmaf(v1.x, wr[4 * 32 + c], acc[c]);
            acc[c] = fmaf(v1.y, wr[5 * 32 + c], acc[c]);
            acc[c] = fmaf(v1.z, wr[6 * 32 + c], acc[c]);
            acc[c] = fmaf(v1.w, wr[7 * 32 + c], acc[c]);
            acc[c] = fmaf(v2.x, wr[8 * 32 + c], acc[c]);
            acc[c] = fmaf(v2.y, wr[9 * 32 + c], acc[c]);
            acc[c] = fmaf(v2.z, wr[10 * 32 + c], acc[c]);
            acc[c] = fmaf(v2.w, wr[11 * 32 + c], acc[c]);
            acc[c] = fmaf(v3.x, wr[12 * 32 + c], acc[c]);
            acc[c] = fmaf(v3.y, wr[13 * 32 + c], acc[c]);
            acc[c] = fmaf(v3.z, wr[14 * 32 + c], acc[c]);
            acc[c] = fmaf(v3.w, wr[15 * 32 + c], acc[c]);
        }
        v0 = n0; v1 = n1; v2 = n2; v3 = n3;
    }
    float di = dinv[row];
    float* o = hs1 + (size_t)row * F_HID;
#pragma unroll
    for (int c = 0; c < 32; c += 4) {
        float4 v = make_float4(acc[c] * di, acc[c + 1] * di, acc[c + 2] * di, acc[c + 3] * di);
        *(float4*)(o + c) = v;
    }
}

// ---------------- gather layer 1: out1 = relu(dinv*(hs1_self + sum hs1[src]) + b1) ----------------
__global__ __launch_bounds__(256) void k_gather1(const float* __restrict__ hs1,
                                                 const int* __restrict__ csr,
                                                 const int* __restrict__ row_ptr,
                                                 const float* __restrict__ dinv,
                                                 const float* __restrict__ b1,
                                                 float* __restrict__ out1, int N) {
    int node = blockIdx.x * 4 + (threadIdx.x >> 6);
    if (node >= N) return;
    int lane = threadIdx.x & 63;
    int half = lane >> 5, c = lane & 31;
    int beg = row_ptr[node], end = row_ptr[node + 1];
    float a0 = 0.f, a1 = 0.f;
    int e = beg + half;
    while (e + 2 < end) {
        int s0 = csr[e], s1 = csr[e + 2];
        a0 += hs1[(size_t)s0 * F_HID + c];
        a1 += hs1[(size_t)s1 * F_HID + c];
        e += 4;
    }
    if (e < end) a0 += hs1[(size_t)csr[e] * F_HID + c];
    float acc = a0 + a1;
    acc += __shfl_xor(acc, 32, 64);
    float self = hs1[(size_t)node * F_HID + c];
    float v = dinv[node] * (acc + self) + b1[c];
    v = fmaxf(v, 0.f);
    if (half == 0) out1[(size_t)node * F_HID + c] = v;
}

// ---------------- GEMM2: hs2 = (out1 @ W2) * dinv  [N,32]x[32,16] ----------------
__global__ __launch_bounds__(256) void k_gemm2(const float* __restrict__ in,
                                               const float* __restrict__ W,
                                               const float* __restrict__ dinv,
                                               float* __restrict__ hs2, int N) {
    int row = blockIdx.x * 256 + threadIdx.x;
    if (row >= N) return;
    const float4* xr = (const float4*)(in + (size_t)row * F_HID);
    float acc[16];
#pragma unroll
    for (int c = 0; c < 16; ++c) acc[c] = 0.f;
#pragma unroll
    for (int k4 = 0; k4 < 8; ++k4) {
        float4 xv = xr[k4];
        const float* wr = W + k4 * 64;
#pragma unroll
        for (int c = 0; c < 16; ++c) {
            acc[c] = fmaf(xv.x, wr[c], acc[c]);
            acc[c] = fmaf(xv.y, wr[16 + c], acc[c]);
            acc[c] = fmaf(xv.z, wr[32 + c], acc[c]);
            acc[c] = fmaf(xv.w, wr[48 + c], acc[c]);
        }
    }
    float di = dinv[row];
    float* o = hs2 + (size_t)row * N_CLS;
#pragma unroll
    for (int c = 0; c < 16; c += 4) {
        float4 v = make_float4(acc[c] * di, acc[c + 1] * di, acc[c + 2] * di, acc[c + 3] * di);
        *(float4*)(o + c) = v;
    }
}

// ---------------- gather layer 2 + bias + log_softmax ----------------
__global__ __launch_bounds__(256) void k_gather2(const float* __restrict__ hs2,
                                                 const int* __restrict__ csr,
                                                 const int* __restrict__ row_ptr,
                                                 const float* __restrict__ dinv,
                                                 const float* __restrict__ b2,
                                                 float* __restrict__ out, int N) {
    int node = blockIdx.x * 4 + (threadIdx.x >> 6);
    if (node >= N) return;
    int lane = threadIdx.x & 63;
    int q = lane >> 4, c = lane & 15;
    int beg = row_ptr[node], end = row_ptr[node + 1];
    float acc = 0.f;
    for (int e = beg + q; e < end; e += 4)
        acc += hs2[(size_t)csr[e] * N_CLS + c];
    acc += __shfl_xor(acc, 16, 64);
    acc += __shfl_xor(acc, 32, 64);
    float self = hs2[(size_t)node * N_CLS + c];
    float v = dinv[node] * (acc + self) + b2[c];
    // log_softmax over the 16 lanes of each q-group (all q identical now)
    float m = v;
#pragma unroll
    for (int off = 1; off < 16; off <<= 1) m = fmaxf(m, __shfl_xor(m, off, 64));
    float ex = __expf(v - m);
    float s = ex;
#pragma unroll
    for (int off = 1; off < 16; off <<= 1) s += __shfl_xor(s, off, 64);
    if (q == 0) out[(size_t)node * N_CLS + c] = v - m - __logf(s);
}

// ---------------- launch ----------------
extern "C" void kernel_launch(void* const* d_in, const int* in_sizes, int n_in,
                              void* d_out, int out_size, void* d_ws, size_t ws_size,
                              hipStream_t stream) {
    const float* x  = (const float*)d_in[0];
    const void* edges = d_in[1];
    const float* W1 = (const float*)d_in[2];
    const float* b1 = (const float*)d_in[3];
    const float* W2 = (const float*)d_in[4];
    const float* b2 = (const float*)d_in[5];
    float* out = (float*)d_out;

    const int N = in_sizes[0] / F_IN;   // 100000
    const int E = in_sizes[1] / 2;      // 3200000

    char* w = (char*)d_ws;
    size_t off = 0;
    auto take = [&](size_t bytes) {
        size_t o = off;
        off += (bytes + 15) & ~(size_t)15;
        return o;
    };
    float* hs1   = (float*)(w + take((size_t)N * F_HID * 4));
    float* out1  = (float*)(w + take((size_t)N * F_HID * 4));
    float* dinv  = (float*)(w + take((size_t)N * 4));
    int* counts  = (int*)(w + take((size_t)N * 4));
    int* cursor  = (int*)(w + take((size_t)N * 4));
    int* row_ptr = (int*)(w + take(((size_t)N + 1) * 4));
    int* bsums   = (int*)(w + take(512));
    int* flag    = (int*)(w + take(16));
    int* csr     = (int*)(w + take((size_t)E * 4));
    float* hs2   = hs1;  // hs1 dead after gather1 → reuse for layer 2

    const int NB = (N + 1023) / 1024;  // scan blocks (<=128)

    hipLaunchKernelGGL(k_detect, dim3(1), dim3(64), 0, stream, (const int*)edges, flag);
    hipMemsetAsync(counts, 0, (size_t)N * 4, stream);
    hipMemsetAsync(cursor, 0, (size_t)N * 4, stream);
    hipLaunchKernelGGL(k_hist, dim3(1024), dim3(256), 0, stream, edges, flag, counts, E);
    hipLaunchKernelGGL(k_dinv, dim3((N + 255) / 256), dim3(256), 0, stream, counts, dinv, N);
    hipLaunchKernelGGL(k_scan1, dim3(NB), dim3(256), 0, stream, counts, bsums, N);
    hipLaunchKernelGGL(k_scan2, dim3(1), dim3(128), 0, stream, bsums, NB);
    hipLaunchKernelGGL(k_scan3, dim3(NB), dim3(256), 0, stream, counts, bsums, row_ptr, N, E);
    hipLaunchKernelGGL(k_fill, dim3(1024), dim3(256), 0, stream, edges, flag, row_ptr, cursor, csr, E);
    hipLaunchKernelGGL(k_gemm1, dim3((N + 63) / 64), dim3(64), 0, stream, x, W1, dinv, hs1, N);
    hipLaunchKernelGGL(k_gather1, dim3((N + 3) / 4), dim3(256), 0, stream, hs1, csr, row_ptr, dinv, b1, out1, N);
    hipLaunchKernelGGL(k_gemm2, dim3((N + 255) / 256), dim3(256), 0, stream, out1, W2, dinv, hs2, N);
    hipLaunchKernelGGL(k_gather2, dim3((N + 3) / 4), dim3(256), 0, stream, hs2, csr, row_ptr, dinv, b2, out, N);
}